// Round 3
// baseline (252.214 us; speedup 1.0000x reference)
//
#include <hip/hip_runtime.h>
#include <cstddef>

#define H 16
#define D 1024
#define DH 64
#define L 512

typedef __attribute__((ext_vector_type(8))) short bf16x8;
typedef __attribute__((ext_vector_type(4))) short bf16x4;
typedef __attribute__((ext_vector_type(4))) float f32x4;

__device__ inline short f2bf(float x) {
    union { float f; unsigned u; } c; c.f = x;
    unsigned r = (c.u + 0x7FFFu + ((c.u >> 16) & 1u)) >> 16;
    return (short)r;
}
__device__ inline float bf2f(short x) {
    union { float f; unsigned u; } c;
    c.u = ((unsigned)(unsigned short)x) << 16; return c.f;
}

__device__ inline void gload_lds16(const void* g, void* l) {
    __builtin_amdgcn_global_load_lds(
        (const __attribute__((address_space(1))) unsigned int*)g,
        (__attribute__((address_space(3))) unsigned int*)l,
        16, 0, 0);
}

// ---------------- prep: fp32->bf16 convert (5 regions) + 4 weight transposes ----------------
struct PrepArgs {
    const float* csrc[5]; short* cdst[5]; int cn[5];
    const float* W[4]; short* T[4];
};

__global__ __launch_bounds__(256) void prep_kernel(PrepArgs a) {
    const int y = blockIdx.y;
    if (y < 5) {
        const float* s = a.csrc[y];
        short* d = a.cdst[y];
        int n = a.cn[y];
        int i = (blockIdx.x * 256 + threadIdx.x) * 8;
        if (i >= n) return;
        float4 x0 = *(const float4*)(s + i);
        float4 x1 = *(const float4*)(s + i + 4);
        bf16x8 o;
        o[0] = f2bf(x0.x); o[1] = f2bf(x0.y); o[2] = f2bf(x0.z); o[3] = f2bf(x0.w);
        o[4] = f2bf(x1.x); o[5] = f2bf(x1.y); o[6] = f2bf(x1.z); o[7] = f2bf(x1.w);
        *(bf16x8*)(d + i) = o;
    } else {
        const float* W = a.W[y - 5];
        short* T = a.T[y - 5];
        int idx = blockIdx.x * 256 + threadIdx.x;
        if (idx >= 1024 * 128) return;
        int n = idx & 1023;
        int k0 = (idx >> 10) << 3;
        bf16x8 o;
        #pragma unroll
        for (int kk = 0; kk < 8; ++kk)
            o[kk] = f2bf(W[(size_t)(k0 + kk) * 1024 + n]);
        *(bf16x8*)(T + (size_t)n * 1024 + k0) = o;
    }
}

// ---------------- MFMA GEMM: 128x128 tile (m97-class), global_load_lds + XOR swizzle ----------------
#define BM 128
#define BN 128
#define BKK 64

struct GemmBatch {
    const short* A[3]; const short* Bt[3]; const float* bias[3];
    void* out[3]; float scale[3]; int mode[3];
};

__global__ __launch_bounds__(256) void gemm_mfma_kernel(GemmBatch P, int M, int N, int K) {
    const int z = blockIdx.z;
    const short* __restrict__ A  = P.A[z];
    const short* __restrict__ Bt = P.Bt[z];
    const float* __restrict__ bias = P.bias[z];
    const float scale = P.scale[z];
    const int mode = P.mode[z];

    // 34816 B: As(16KB) + Bs(16KB) during main loop; reused as 128x136 transpose buf (mode 2)
    __shared__ short lds[17408];
    short* As = lds;
    short* Bs = lds + 8192;

    const int tid = threadIdx.x;
    const int wave = tid >> 6, lane = tid & 63;
    const int fm = lane & 15, quad = lane >> 4;
    const int wr = wave >> 1, wc = wave & 1;     // 2x2 wave grid, each wave 64x64
    const int m0 = blockIdx.y * BM, n0 = blockIdx.x * BN;

    int srow[4], scol[4];
    #pragma unroll
    for (int t = 0; t < 4; ++t) {
        int s = (wave * 4 + t) * 64 + lane;
        int row = s >> 3;
        int u = (s & 7) ^ (row & 7);
        srow[t] = row; scol[t] = u * 8;
    }

    int aoff[4][2], boff[4][2];
    #pragma unroll
    for (int mt = 0; mt < 4; ++mt)
        #pragma unroll
        for (int kst = 0; kst < 2; ++kst) {
            int row = wr * 64 + mt * 16 + fm;
            int u = quad + 4 * kst;
            aoff[mt][kst] = row * 64 + ((u ^ (row & 7)) * 8);
        }
    #pragma unroll
    for (int nt = 0; nt < 4; ++nt)
        #pragma unroll
        for (int kst = 0; kst < 2; ++kst) {
            int row = wc * 64 + nt * 16 + fm;
            int u = quad + 4 * kst;
            boff[nt][kst] = row * 64 + ((u ^ (row & 7)) * 8);
        }

    f32x4 acc[4][4];
    #pragma unroll
    for (int mt = 0; mt < 4; ++mt)
        #pragma unroll
        for (int nt = 0; nt < 4; ++nt) acc[mt][nt] = (f32x4){0.f, 0.f, 0.f, 0.f};

    for (int k0 = 0; k0 < K; k0 += BKK) {
        __syncthreads();
        #pragma unroll
        for (int t = 0; t < 4; ++t)
            gload_lds16(A + (size_t)(m0 + srow[t]) * K + k0 + scol[t],
                        As + (wave * 4 + t) * 512);
        #pragma unroll
        for (int t = 0; t < 4; ++t)
            gload_lds16(Bt + (size_t)(n0 + srow[t]) * K + k0 + scol[t],
                        Bs + (wave * 4 + t) * 512);
        __syncthreads();
        #pragma unroll
        for (int kst = 0; kst < 2; ++kst) {
            bf16x8 af[4], bfr[4];
            #pragma unroll
            for (int mt = 0; mt < 4; ++mt)
                af[mt] = *(const bf16x8*)(As + aoff[mt][kst]);
            #pragma unroll
            for (int nt = 0; nt < 4; ++nt)
                bfr[nt] = *(const bf16x8*)(Bs + boff[nt][kst]);
            #pragma unroll
            for (int mt = 0; mt < 4; ++mt)
                #pragma unroll
                for (int nt = 0; nt < 4; ++nt)
                    acc[mt][nt] = __builtin_amdgcn_mfma_f32_16x16x32_bf16(
                        af[mt], bfr[nt], acc[mt][nt], 0, 0, 0);
        }
    }

    if (mode == 2) {
        __syncthreads();
        short (*T)[136] = (short(*)[136])&lds[0];
        #pragma unroll
        for (int mt = 0; mt < 4; ++mt)
            #pragma unroll
            for (int nt = 0; nt < 4; ++nt) {
                int nn = wc * 64 + nt * 16 + fm;
                float bv = bias[n0 + nn];
                #pragma unroll
                for (int r = 0; r < 4; ++r) {
                    int mm = wr * 64 + mt * 16 + quad * 4 + r;
                    T[nn][mm] = f2bf((acc[mt][nt][r] + bv) * scale);
                }
            }
        __syncthreads();
        int b = m0 >> 9;
        int ibase = m0 & (L - 1);
        int n = tid >> 1, half = tid & 1;
        int hh = (n0 + n) >> 6, d = n & 63;
        short* dst = (short*)P.out[z] + (((size_t)(b * H + hh) * DH + d) * L) + ibase + half * 64;
        #pragma unroll
        for (int c = 0; c < 8; ++c)
            *(bf16x8*)(dst + c * 8) = *(const bf16x8*)(&T[n][half * 64 + c * 8]);
    } else {
        #pragma unroll
        for (int mt = 0; mt < 4; ++mt)
            #pragma unroll
            for (int nt = 0; nt < 4; ++nt) {
                int n = n0 + wc * 64 + nt * 16 + fm;
                float bv = bias[n];
                #pragma unroll
                for (int r = 0; r < 4; ++r) {
                    int m = m0 + wr * 64 + mt * 16 + quad * 4 + r;
                    float val = (acc[mt][nt][r] + bv) * scale;
                    if (mode == 0) {
                        ((float*)P.out[z])[(size_t)m * N + n] = val;
                    } else {
                        int b = m >> 9, i = m & (L - 1);
                        int h = n >> 6, dd = n & (DH - 1);
                        ((short*)P.out[z])[(((size_t)(b * H + h) * L + i) * DH) + dd] = f2bf(val);
                    }
                }
            }
    }
}

// ---------------- ast scores -> Sast bf16 [b][i][h][j] ----------------
__global__ __launch_bounds__(256) void ast_kernel(
    const short* __restrict__ Qb, const int* __restrict__ mat,
    const short* __restrict__ semb, const short* __restrict__ vemb,
    short* __restrict__ Sast)
{
    const int i = blockIdx.x, b = blockIdx.y;
    const int tid = threadIdx.x;
    const int wave = tid >> 6, lane = tid & 63;
    const int fm = lane & 15, quad = lane >> 4;
    __shared__ short Sl[H][L + 8];

    const short* qp = Qb + (((size_t)(b * H + fm) * L + i) * DH);
    bf16x8 a0 = *(const bf16x8*)(qp + quad * 8);
    bf16x8 a1 = *(const bf16x8*)(qp + 32 + quad * 8);

    const int* mrow = mat + ((size_t)b * L + i) * L;

    int idxs[8];
    const short* ebase[8];
    #pragma unroll
    for (int t = 0; t < 8; ++t) {
        int j = (wave + t * 4) * 16 + fm;
        idxs[t] = mrow[j];
    }
    #pragma unroll
    for (int t = 0; t < 8; ++t) {
        int j = (wave + t * 4) * 16 + fm;
        ebase[t] = ((j & 1) ? vemb : semb) + (size_t)idxs[t] * DH;
    }

    #pragma unroll
    for (int t = 0; t < 8; ++t) {
        int j = (wave + t * 4) * 16 + fm;
        bf16x8 b0 = *(const bf16x8*)(ebase[t] + quad * 8);
        bf16x8 b1 = *(const bf16x8*)(ebase[t] + 32 + quad * 8);
        f32x4 c = {0.f, 0.f, 0.f, 0.f};
        c = __builtin_amdgcn_mfma_f32_16x16x32_bf16(a0, b0, c, 0, 0, 0);
        c = __builtin_amdgcn_mfma_f32_16x16x32_bf16(a1, b1, c, 0, 0, 0);
        #pragma unroll
        for (int r = 0; r < 4; ++r)
            Sl[quad * 4 + r][j] = f2bf(c[r]);
    }
    __syncthreads();
    int hh = tid >> 4, j0 = (tid & 15) * 32;
    short* dst = Sast + ((((size_t)b * L + i) * H + hh) * L) + j0;
    #pragma unroll
    for (int c = 0; c < 4; ++c)
        *(bf16x8*)(dst + c * 8) = *(const bf16x8*)(&Sl[hh][j0 + c * 8]);
}

// ---------------- fused attn: per-wave full-row ownership, swapped QK^T ----------------
// Swapped mfma(K,Q) makes C=[j][i]: lane (fm,quad) owns row i=fm, j = t*16+quad*4+r.
// Softmax is 128 in-lane ops + 2 quad-shuffles; ONE barrier total (Sast staging).
// Each wave owns 16 i-rows end-to-end; P transpose for PV via wave-private LDS rows.
#define PPITCH 520   // shorts; 1040 B row pitch (16B-aligned, bank-friendly)

__global__ __launch_bounds__(256, 2) void attn_fused_kernel(
    const short* __restrict__ Qb, const short* __restrict__ Kb,
    const short* __restrict__ Vt, const short* __restrict__ Sast,
    const unsigned char* __restrict__ mask,
    float* __restrict__ attn, short* __restrict__ ctx)
{
    const int i0 = blockIdx.x * 64;
    const int h = blockIdx.y;
    const int b = blockIdx.z;
    const int tid = threadIdx.x;
    const int wave = tid >> 6, lane = tid & 63;
    const int fm = lane & 15, quad = lane >> 4;

    __shared__ short Pb[64 * PPITCH];   // 66560 B: Sast staging, then P (bf16)

    // block-wide coalesced staging of Sast rows i0..i0+63 (head h)
    {
        const short* base = Sast + (((size_t)b * L + i0) * H + h) * L;
        #pragma unroll
        for (int p = 0; p < 16; ++p) {
            int row = p * 4 + (tid >> 6);
            int col = (tid & 63) * 8;
            *(bf16x8*)(&Pb[row * PPITCH + col]) =
                *(const bf16x8*)(base + (size_t)row * (H * L) + col);
        }
    }

    const int iw = i0 + wave * 16;       // this wave's 16 rows
    // Q as B-operand: lane holds col i=fm, k-chunk quad
    const short* qp = Qb + (((size_t)(b * H + h) * L + iw + fm) * DH);
    bf16x8 q0 = *(const bf16x8*)(qp + quad * 8);
    bf16x8 q1 = *(const bf16x8*)(qp + 32 + quad * 8);
    const short* Kbase = Kb + ((size_t)(b * H + h) * L) * DH;
    const unsigned char* mrow = mask + (size_t)b * L;

    __syncthreads();   // staging complete; hereafter each wave touches only its own rows

    short* Prow = &Pb[(wave * 16 + fm) * PPITCH];   // LDS row for i = fm of this wave

    // QK^T swapped: s[t][r] = score(i = iw+fm, j = t*16+quad*4+r)
    float s[32][4];
    float mx = -3.0e38f;
    #pragma unroll
    for (int t = 0; t < 32; ++t) {
        const short* kr = Kbase + (size_t)(t * 16 + fm) * DH;   // A-operand: row j
        bf16x8 k0 = *(const bf16x8*)(kr + quad * 8);
        bf16x8 k1 = *(const bf16x8*)(kr + 32 + quad * 8);
        f32x4 c = {0.f, 0.f, 0.f, 0.f};
        c = __builtin_amdgcn_mfma_f32_16x16x32_bf16(k0, q0, c, 0, 0, 0);
        c = __builtin_amdgcn_mfma_f32_16x16x32_bf16(k1, q1, c, 0, 0, 0);
        bf16x4 sa = *(const bf16x4*)(&Prow[t * 16 + quad * 4]);          // Sast add
        unsigned mku = *(const unsigned*)(mrow + t * 16 + quad * 4);     // 4 mask bytes
        #pragma unroll
        for (int r = 0; r < 4; ++r) {
            float sv = c[r] + bf2f(sa[r]);
            sv = ((mku >> (8 * r)) & 255u) ? -1e18f : sv;
            s[t][r] = sv;
            mx = fmaxf(mx, sv);
        }
    }

    // full row max: in-lane done; combine the 4 quads sharing this fm
    mx = fmaxf(mx, __shfl_xor(mx, 16));
    mx = fmaxf(mx, __shfl_xor(mx, 32));

    float sum = 0.f;
    #pragma unroll
    for (int t = 0; t < 32; ++t)
        #pragma unroll
        for (int r = 0; r < 4; ++r) {
            float e = __expf(s[t][r] - mx);
            s[t][r] = e;
            sum += e;
        }
    sum += __shfl_xor(sum, 16);
    sum += __shfl_xor(sum, 32);
    float inv = 1.f / sum;

    // normalize -> bf16 P (LDS, packed b64) + direct fp32 attn store (bf16-rounded)
    float* arow = attn + (((size_t)(b * H + h) * L + iw + fm) * L);
    #pragma unroll
    for (int t = 0; t < 32; ++t) {
        bf16x4 pw;
        #pragma unroll
        for (int r = 0; r < 4; ++r)
            pw[r] = f2bf(s[t][r] * inv);
        *(bf16x4*)(&Prow[t * 16 + quad * 4]) = pw;
        float4 v;
        v.x = bf2f(pw[0]); v.y = bf2f(pw[1]); v.z = bf2f(pw[2]); v.w = bf2f(pw[3]);
        *(float4*)(arow + t * 16 + quad * 4) = v;
    }

    // PV: wave computes its 16 rows x all 64 d. A = P rows (LDS, own-wave writes -> compiler waits)
    const short* Vbase = Vt + ((size_t)(b * H + h) * DH) * L;
    f32x4 o[4];
    #pragma unroll
    for (int dt = 0; dt < 4; ++dt) o[dt] = (f32x4){0.f, 0.f, 0.f, 0.f};
    #pragma unroll
    for (int ks = 0; ks < L; ks += 32) {
        bf16x8 pa = *(const bf16x8*)(&Prow[ks + quad * 8]);
        #pragma unroll
        for (int dt = 0; dt < 4; ++dt) {
            bf16x8 vb = *(const bf16x8*)(Vbase + (size_t)(dt * 16 + fm) * L + ks + quad * 8);
            o[dt] = __builtin_amdgcn_mfma_f32_16x16x32_bf16(pa, vb, o[dt], 0, 0, 0);
        }
    }
    #pragma unroll
    for (int dt = 0; dt < 4; ++dt)
        #pragma unroll
        for (int r = 0; r < 4; ++r)
            ctx[((size_t)b * L + iw + quad * 4 + r) * D + h * DH + dt * 16 + fm] = f2bf(o[dt][r]);
}

extern "C" void kernel_launch(void* const* d_in, const int* in_sizes, int n_in,
                              void* d_out, int out_size, void* d_ws, size_t ws_size,
                              hipStream_t stream) {
    const float* key_in   = (const float*)d_in[0];
    const float* value_in = (const float*)d_in[1];
    const float* query_in = (const float*)d_in[2];
    const int*   mat      = (const int*)d_in[3];
    const unsigned char* mask = (const unsigned char*)d_in[4];
    const float* Wq = (const float*)d_in[5];
    const float* bq = (const float*)d_in[6];
    const float* Wk = (const float*)d_in[7];
    const float* bk = (const float*)d_in[8];
    const float* Wv = (const float*)d_in[9];
    const float* bv = (const float*)d_in[10];
    const float* Wo = (const float*)d_in[11];
    const float* bo = (const float*)d_in[12];
    const float* struct_emb = (const float*)d_in[13];
    const float* value_emb  = (const float*)d_in[14];

    const int B = in_sizes[2] / (L * D);   // 4
    const int M = B * L;                   // 2048

    short* p = (short*)d_ws;
    short* xk  = p;  p += (size_t)M * D;
    short* xv  = p;  p += (size_t)M * D;
    short* xq  = p;  p += (size_t)M * D;
    short* WqT = p;  p += (size_t)D * D;
    short* WkT = p;  p += (size_t)D * D;
    short* WvT = p;  p += (size_t)D * D;
    short* WoT = p;  p += (size_t)D * D;
    short* semb = p; p += 16384;
    short* vemb = p; p += (size_t)in_sizes[14];
    short* Qb = p;   p += (size_t)M * D;
    short* Kb = p;   p += (size_t)M * D;
    short* Vt = p;   p += (size_t)M * D;
    short* Sast = p; p += (size_t)B * L * H * L;
    short* ctx = xk;   // dead after QKV projections; reused stream-ordered

    float* out_p  = (float*)d_out;
    float* attn_p = out_p + (size_t)M * D;

    PrepArgs pa;
    pa.csrc[0] = key_in;     pa.cdst[0] = xk;   pa.cn[0] = M * D;
    pa.csrc[1] = value_in;   pa.cdst[1] = xv;   pa.cn[1] = M * D;
    pa.csrc[2] = query_in;   pa.cdst[2] = xq;   pa.cn[2] = M * D;
    pa.csrc[3] = struct_emb; pa.cdst[3] = semb; pa.cn[3] = in_sizes[13];
    pa.csrc[4] = value_emb;  pa.cdst[4] = vemb; pa.cn[4] = in_sizes[14];
    pa.W[0] = Wq; pa.W[1] = Wk; pa.W[2] = Wv; pa.W[3] = Wo;
    pa.T[0] = WqT; pa.T[1] = WkT; pa.T[2] = WvT; pa.T[3] = WoT;
    prep_kernel<<<dim3((M * D) / 2048, 9), 256, 0, stream>>>(pa);

    GemmBatch qkv;
    qkv.A[0] = xq; qkv.Bt[0] = WqT; qkv.bias[0] = bq; qkv.out[0] = Qb; qkv.scale[0] = 0.125f; qkv.mode[0] = 1;
    qkv.A[1] = xk; qkv.Bt[1] = WkT; qkv.bias[1] = bk; qkv.out[1] = Kb; qkv.scale[1] = 1.0f;   qkv.mode[1] = 1;
    qkv.A[2] = xv; qkv.Bt[2] = WvT; qkv.bias[2] = bv; qkv.out[2] = Vt; qkv.scale[2] = 1.0f;   qkv.mode[2] = 2;
    gemm_mfma_kernel<<<dim3(D / BN, M / BM, 3), 256, 0, stream>>>(qkv, M, D, D);

    ast_kernel<<<dim3(L, B), 256, 0, stream>>>(Qb, mat, semb, vemb, Sast);

    attn_fused_kernel<<<dim3(L / 64, H, B), 256, 0, stream>>>(
        Qb, Kb, Vt, Sast, mask, attn_p, ctx);

    GemmBatch fin;
    fin.A[0] = ctx; fin.Bt[0] = WoT; fin.bias[0] = bo; fin.out[0] = out_p; fin.scale[0] = 1.0f; fin.mode[0] = 0;
    fin.A[1] = ctx; fin.Bt[1] = WoT; fin.bias[1] = bo; fin.out[1] = out_p; fin.scale[1] = 1.0f; fin.mode[1] = 0;
    fin.A[2] = ctx; fin.Bt[2] = WoT; fin.bias[2] = bo; fin.out[2] = out_p; fin.scale[2] = 1.0f; fin.mode[2] = 0;
    gemm_mfma_kernel<<<dim3(D / BN, M / BM, 1), 256, 0, stream>>>(fin, M, D, D);
}

// Round 4
// 237.422 us; speedup vs baseline: 1.0623x; 1.0623x over previous
//
#include <hip/hip_runtime.h>
#include <cstddef>

#define H 16
#define D 1024
#define DH 64
#define L 512

typedef __attribute__((ext_vector_type(8))) short bf16x8;
typedef __attribute__((ext_vector_type(4))) short bf16x4;
typedef __attribute__((ext_vector_type(4))) float f32x4;

__device__ inline short f2bf(float x) {
    union { float f; unsigned u; } c; c.f = x;
    unsigned r = (c.u + 0x7FFFu + ((c.u >> 16) & 1u)) >> 16;
    return (short)r;
}
__device__ inline float bf2f(short x) {
    union { float f; unsigned u; } c;
    c.u = ((unsigned)(unsigned short)x) << 16; return c.f;
}

__device__ inline void gload_lds16(const void* g, void* l) {
    __builtin_amdgcn_global_load_lds(
        (const __attribute__((address_space(1))) unsigned int*)g,
        (__attribute__((address_space(3))) unsigned int*)l,
        16, 0, 0);
}

// ---------------- prep: fp32->bf16 convert (5 regions) + 4 weight transposes ----------------
struct PrepArgs {
    const float* csrc[5]; short* cdst[5]; int cn[5];
    const float* W[4]; short* T[4];
};

__global__ __launch_bounds__(256) void prep_kernel(PrepArgs a) {
    const int y = blockIdx.y;
    if (y < 5) {
        const float* s = a.csrc[y];
        short* d = a.cdst[y];
        int n = a.cn[y];
        int i = (blockIdx.x * 256 + threadIdx.x) * 8;
        if (i >= n) return;
        float4 x0 = *(const float4*)(s + i);
        float4 x1 = *(const float4*)(s + i + 4);
        bf16x8 o;
        o[0] = f2bf(x0.x); o[1] = f2bf(x0.y); o[2] = f2bf(x0.z); o[3] = f2bf(x0.w);
        o[4] = f2bf(x1.x); o[5] = f2bf(x1.y); o[6] = f2bf(x1.z); o[7] = f2bf(x1.w);
        *(bf16x8*)(d + i) = o;
    } else {
        const float* W = a.W[y - 5];
        short* T = a.T[y - 5];
        int idx = blockIdx.x * 256 + threadIdx.x;
        if (idx >= 1024 * 128) return;
        int n = idx & 1023;
        int k0 = (idx >> 10) << 3;
        bf16x8 o;
        #pragma unroll
        for (int kk = 0; kk < 8; ++kk)
            o[kk] = f2bf(W[(size_t)(k0 + kk) * 1024 + n]);
        *(bf16x8*)(T + (size_t)n * 1024 + k0) = o;
    }
}

// ---------------- MFMA GEMM, m97-style: global_load_lds + XOR-swizzled LDS ----------------
// BM=128/BN=64: 768-block grid for QKV (3/CU), 256 for out-proj (1/CU) — grid balance
// beats per-block efficiency at these GEMM sizes (round-3 lesson: 128x128 tile = half CUs idle).
#define BM 128
#define BN 64
#define BKK 64

struct GemmBatch {
    const short* A[3]; const short* Bt[3]; const float* bias[3];
    void* out[3]; float scale[3]; int mode[3];
};

__global__ __launch_bounds__(256) void gemm_mfma_kernel(GemmBatch P, int M, int N, int K) {
    const int z = blockIdx.z;
    const short* __restrict__ A  = P.A[z];
    const short* __restrict__ Bt = P.Bt[z];
    const float* __restrict__ bias = P.bias[z];
    const float scale = P.scale[z];
    const int mode = P.mode[z];

    __shared__ short lds[(BM + BN) * BKK];
    short* As = lds;
    short* Bs = lds + BM * BKK;

    const int tid = threadIdx.x;
    const int wave = tid >> 6, lane = tid & 63;
    const int fm = lane & 15, quad = lane >> 4;
    const int m0 = blockIdx.y * BM, n0 = blockIdx.x * BN;

    int arow[4], acol[4];
    #pragma unroll
    for (int t = 0; t < 4; ++t) {
        int s = (wave * 4 + t) * 64 + lane;
        int row = s >> 3;
        int u = (s & 7) ^ (row & 7);
        arow[t] = row; acol[t] = u * 8;
    }
    int brow[2], bcol[2];
    #pragma unroll
    for (int t = 0; t < 2; ++t) {
        int s = (wave * 2 + t) * 64 + lane;
        int row = s >> 3;
        int u = (s & 7) ^ (row & 7);
        brow[t] = row; bcol[t] = u * 8;
    }

    int aoff[2][2], boff[4][2];
    #pragma unroll
    for (int mt = 0; mt < 2; ++mt)
        #pragma unroll
        for (int kst = 0; kst < 2; ++kst) {
            int row = wave * 32 + mt * 16 + fm;
            int u = quad + 4 * kst;
            aoff[mt][kst] = row * 64 + ((u ^ (row & 7)) * 8);
        }
    #pragma unroll
    for (int nt = 0; nt < 4; ++nt)
        #pragma unroll
        for (int kst = 0; kst < 2; ++kst) {
            int row = nt * 16 + fm;
            int u = quad + 4 * kst;
            boff[nt][kst] = row * 64 + ((u ^ (row & 7)) * 8);
        }

    f32x4 acc[2][4];
    #pragma unroll
    for (int mt = 0; mt < 2; ++mt)
        #pragma unroll
        for (int nt = 0; nt < 4; ++nt) acc[mt][nt] = (f32x4){0.f, 0.f, 0.f, 0.f};

    for (int k0 = 0; k0 < K; k0 += BKK) {
        __syncthreads();
        #pragma unroll
        for (int t = 0; t < 4; ++t)
            gload_lds16(A + (size_t)(m0 + arow[t]) * K + k0 + acol[t],
                        As + (wave * 4 + t) * 512);
        #pragma unroll
        for (int t = 0; t < 2; ++t)
            gload_lds16(Bt + (size_t)(n0 + brow[t]) * K + k0 + bcol[t],
                        Bs + (wave * 2 + t) * 512);
        __syncthreads();
        #pragma unroll
        for (int kst = 0; kst < 2; ++kst) {
            bf16x8 af[2], bfr[4];
            af[0] = *(const bf16x8*)(As + aoff[0][kst]);
            af[1] = *(const bf16x8*)(As + aoff[1][kst]);
            #pragma unroll
            for (int nt = 0; nt < 4; ++nt)
                bfr[nt] = *(const bf16x8*)(Bs + boff[nt][kst]);
            #pragma unroll
            for (int mt = 0; mt < 2; ++mt)
                #pragma unroll
                for (int nt = 0; nt < 4; ++nt)
                    acc[mt][nt] = __builtin_amdgcn_mfma_f32_16x16x32_bf16(
                        af[mt], bfr[nt], acc[mt][nt], 0, 0, 0);
        }
    }

    if (mode == 2) {
        __syncthreads();
        short (*T)[BM + 8] = (short(*)[BM + 8])&lds[0];
        #pragma unroll
        for (int mt = 0; mt < 2; ++mt)
            #pragma unroll
            for (int nt = 0; nt < 4; ++nt) {
                int nn = nt * 16 + fm;
                float bv = bias[n0 + nn];
                #pragma unroll
                for (int r = 0; r < 4; ++r) {
                    int mm = wave * 32 + mt * 16 + quad * 4 + r;
                    T[nn][mm] = f2bf((acc[mt][nt][r] + bv) * scale);
                }
            }
        __syncthreads();
        int b = m0 >> 9;
        int ibase = m0 & (L - 1);
        int hblk = n0 >> 6;
        int n = tid >> 2, seg = (tid & 3) * 32;
        short* dst = (short*)P.out[z] + (((size_t)(b * H + hblk) * DH + n) * L) + ibase + seg;
        #pragma unroll
        for (int c = 0; c < 4; ++c)
            *(bf16x8*)(dst + c * 8) = *(const bf16x8*)(&T[n][seg + c * 8]);
    } else {
        #pragma unroll
        for (int mt = 0; mt < 2; ++mt)
            #pragma unroll
            for (int nt = 0; nt < 4; ++nt) {
                int n = n0 + nt * 16 + fm;
                float bv = bias[n];
                #pragma unroll
                for (int r = 0; r < 4; ++r) {
                    int m = m0 + wave * 32 + mt * 16 + quad * 4 + r;
                    float val = (acc[mt][nt][r] + bv) * scale;
                    if (mode == 0) {
                        ((float*)P.out[z])[(size_t)m * N + n] = val;
                    } else {
                        int b = m >> 9, i = m & (L - 1);
                        int h = n >> 6, d = n & (DH - 1);
                        ((short*)P.out[z])[(((size_t)(b * H + h) * L + i) * DH) + d] = f2bf(val);
                    }
                }
            }
    }
}

// ---------------- ast scores -> Sast bf16 [b][i][h][j] ----------------
__global__ __launch_bounds__(256) void ast_kernel(
    const short* __restrict__ Qb, const int* __restrict__ mat,
    const short* __restrict__ semb, const short* __restrict__ vemb,
    short* __restrict__ Sast)
{
    const int i = blockIdx.x, b = blockIdx.y;
    const int tid = threadIdx.x;
    const int wave = tid >> 6, lane = tid & 63;
    const int fm = lane & 15, quad = lane >> 4;
    __shared__ short Sl[H][L + 8];

    const short* qp = Qb + (((size_t)(b * H + fm) * L + i) * DH);
    bf16x8 a0 = *(const bf16x8*)(qp + quad * 8);
    bf16x8 a1 = *(const bf16x8*)(qp + 32 + quad * 8);

    const int* mrow = mat + ((size_t)b * L + i) * L;

    int idxs[8];
    const short* ebase[8];
    #pragma unroll
    for (int t = 0; t < 8; ++t) {
        int j = (wave + t * 4) * 16 + fm;
        idxs[t] = mrow[j];
    }
    #pragma unroll
    for (int t = 0; t < 8; ++t) {
        int j = (wave + t * 4) * 16 + fm;
        ebase[t] = ((j & 1) ? vemb : semb) + (size_t)idxs[t] * DH;
    }

    #pragma unroll
    for (int t = 0; t < 8; ++t) {
        int j = (wave + t * 4) * 16 + fm;
        bf16x8 b0 = *(const bf16x8*)(ebase[t] + quad * 8);
        bf16x8 b1 = *(const bf16x8*)(ebase[t] + 32 + quad * 8);
        f32x4 c = {0.f, 0.f, 0.f, 0.f};
        c = __builtin_amdgcn_mfma_f32_16x16x32_bf16(a0, b0, c, 0, 0, 0);
        c = __builtin_amdgcn_mfma_f32_16x16x32_bf16(a1, b1, c, 0, 0, 0);
        #pragma unroll
        for (int r = 0; r < 4; ++r)
            Sl[quad * 4 + r][j] = f2bf(c[r]);
    }
    __syncthreads();
    int hh = tid >> 4, j0 = (tid & 15) * 32;
    short* dst = Sast + ((((size_t)b * L + i) * H + hh) * L) + j0;
    #pragma unroll
    for (int c = 0; c < 4; ++c)
        *(bf16x8*)(dst + c * 8) = *(const bf16x8*)(&Sl[hh][j0 + c * 8]);
}

// ---------------- fused attn: per-wave full-row ownership, swapped QK^T ----------------
// Swapped mfma(K,Q) makes C=[j][i]: lane (fm,quad) owns row i=fm, j = t*16+quad*4+r.
// Softmax is 128 in-lane ops + 2 quad-shuffles; ONE barrier total (Sast staging).
// Each wave owns 16 i-rows end-to-end; P transpose for PV via wave-private LDS rows.
#define PPITCH 520   // shorts; 1040 B row pitch (16B-aligned, bank-friendly)

__global__ __launch_bounds__(256, 2) void attn_fused_kernel(
    const short* __restrict__ Qb, const short* __restrict__ Kb,
    const short* __restrict__ Vt, const short* __restrict__ Sast,
    const unsigned char* __restrict__ mask,
    float* __restrict__ attn, short* __restrict__ ctx)
{
    const int i0 = blockIdx.x * 64;
    const int h = blockIdx.y;
    const int b = blockIdx.z;
    const int tid = threadIdx.x;
    const int wave = tid >> 6, lane = tid & 63;
    const int fm = lane & 15, quad = lane >> 4;

    __shared__ short Pb[64 * PPITCH];   // 66560 B: Sast staging, then P (bf16)

    // block-wide coalesced staging of Sast rows i0..i0+63 (head h)
    {
        const short* base = Sast + (((size_t)b * L + i0) * H + h) * L;
        #pragma unroll
        for (int p = 0; p < 16; ++p) {
            int row = p * 4 + (tid >> 6);
            int col = (tid & 63) * 8;
            *(bf16x8*)(&Pb[row * PPITCH + col]) =
                *(const bf16x8*)(base + (size_t)row * (H * L) + col);
        }
    }

    const int iw = i0 + wave * 16;       // this wave's 16 rows
    // Q as B-operand: lane holds col i=fm, k-chunk quad
    const short* qp = Qb + (((size_t)(b * H + h) * L + iw + fm) * DH);
    bf16x8 q0 = *(const bf16x8*)(qp + quad * 8);
    bf16x8 q1 = *(const bf16x8*)(qp + 32 + quad * 8);
    const short* Kbase = Kb + ((size_t)(b * H + h) * L) * DH;
    const unsigned char* mrow = mask + (size_t)b * L;

    __syncthreads();   // staging complete; hereafter each wave touches only its own rows

    short* Prow = &Pb[(wave * 16 + fm) * PPITCH];   // LDS row for i = fm of this wave

    // QK^T swapped: s[t][r] = score(i = iw+fm, j = t*16+quad*4+r)
    float s[32][4];
    float mx = -3.0e38f;
    #pragma unroll
    for (int t = 0; t < 32; ++t) {
        const short* kr = Kbase + (size_t)(t * 16 + fm) * DH;   // A-operand: row j
        bf16x8 k0 = *(const bf16x8*)(kr + quad * 8);
        bf16x8 k1 = *(const bf16x8*)(kr + 32 + quad * 8);
        f32x4 c = {0.f, 0.f, 0.f, 0.f};
        c = __builtin_amdgcn_mfma_f32_16x16x32_bf16(k0, q0, c, 0, 0, 0);
        c = __builtin_amdgcn_mfma_f32_16x16x32_bf16(k1, q1, c, 0, 0, 0);
        bf16x4 sa = *(const bf16x4*)(&Prow[t * 16 + quad * 4]);          // Sast add
        unsigned mku = *(const unsigned*)(mrow + t * 16 + quad * 4);     // 4 mask bytes
        #pragma unroll
        for (int r = 0; r < 4; ++r) {
            float sv = c[r] + bf2f(sa[r]);
            sv = ((mku >> (8 * r)) & 255u) ? -1e18f : sv;
            s[t][r] = sv;
            mx = fmaxf(mx, sv);
        }
    }

    // full row max: in-lane done; combine the 4 quads sharing this fm
    mx = fmaxf(mx, __shfl_xor(mx, 16));
    mx = fmaxf(mx, __shfl_xor(mx, 32));

    float sum = 0.f;
    #pragma unroll
    for (int t = 0; t < 32; ++t)
        #pragma unroll
        for (int r = 0; r < 4; ++r) {
            float e = __expf(s[t][r] - mx);
            s[t][r] = e;
            sum += e;
        }
    sum += __shfl_xor(sum, 16);
    sum += __shfl_xor(sum, 32);
    float inv = 1.f / sum;

    // normalize -> bf16 P (LDS, packed b64) + direct fp32 attn store (bf16-rounded)
    float* arow = attn + (((size_t)(b * H + h) * L + iw + fm) * L);
    #pragma unroll
    for (int t = 0; t < 32; ++t) {
        bf16x4 pw;
        #pragma unroll
        for (int r = 0; r < 4; ++r)
            pw[r] = f2bf(s[t][r] * inv);
        *(bf16x4*)(&Prow[t * 16 + quad * 4]) = pw;
        float4 v;
        v.x = bf2f(pw[0]); v.y = bf2f(pw[1]); v.z = bf2f(pw[2]); v.w = bf2f(pw[3]);
        *(float4*)(arow + t * 16 + quad * 4) = v;
    }

    // PV: wave computes its 16 rows x all 64 d. A = P rows (LDS, own-wave writes -> compiler waits)
    const short* Vbase = Vt + ((size_t)(b * H + h) * DH) * L;
    f32x4 o[4];
    #pragma unroll
    for (int dt = 0; dt < 4; ++dt) o[dt] = (f32x4){0.f, 0.f, 0.f, 0.f};
    #pragma unroll
    for (int ks = 0; ks < L; ks += 32) {
        bf16x8 pa = *(const bf16x8*)(&Prow[ks + quad * 8]);
        #pragma unroll
        for (int dt = 0; dt < 4; ++dt) {
            bf16x8 vb = *(const bf16x8*)(Vbase + (size_t)(dt * 16 + fm) * L + ks + quad * 8);
            o[dt] = __builtin_amdgcn_mfma_f32_16x16x32_bf16(pa, vb, o[dt], 0, 0, 0);
        }
    }
    #pragma unroll
    for (int dt = 0; dt < 4; ++dt)
        #pragma unroll
        for (int r = 0; r < 4; ++r)
            ctx[((size_t)b * L + iw + quad * 4 + r) * D + h * DH + dt * 16 + fm] = f2bf(o[dt][r]);
}

extern "C" void kernel_launch(void* const* d_in, const int* in_sizes, int n_in,
                              void* d_out, int out_size, void* d_ws, size_t ws_size,
                              hipStream_t stream) {
    const float* key_in   = (const float*)d_in[0];
    const float* value_in = (const float*)d_in[1];
    const float* query_in = (const float*)d_in[2];
    const int*   mat      = (const int*)d_in[3];
    const unsigned char* mask = (const unsigned char*)d_in[4];
    const float* Wq = (const float*)d_in[5];
    const float* bq = (const float*)d_in[6];
    const float* Wk = (const float*)d_in[7];
    const float* bk = (const float*)d_in[8];
    const float* Wv = (const float*)d_in[9];
    const float* bv = (const float*)d_in[10];
    const float* Wo = (const float*)d_in[11];
    const float* bo = (const float*)d_in[12];
    const float* struct_emb = (const float*)d_in[13];
    const float* value_emb  = (const float*)d_in[14];

    const int B = in_sizes[2] / (L * D);   // 4
    const int M = B * L;                   // 2048

    short* p = (short*)d_ws;
    short* xk  = p;  p += (size_t)M * D;
    short* xv  = p;  p += (size_t)M * D;
    short* xq  = p;  p += (size_t)M * D;
    short* WqT = p;  p += (size_t)D * D;
    short* WkT = p;  p += (size_t)D * D;
    short* WvT = p;  p += (size_t)D * D;
    short* WoT = p;  p += (size_t)D * D;
    short* semb = p; p += 16384;
    short* vemb = p; p += (size_t)in_sizes[14];
    short* Qb = p;   p += (size_t)M * D;
    short* Kb = p;   p += (size_t)M * D;
    short* Vt = p;   p += (size_t)M * D;
    short* Sast = p; p += (size_t)B * L * H * L;
    short* ctx = xk;   // dead after QKV projections; reused stream-ordered

    float* out_p  = (float*)d_out;
    float* attn_p = out_p + (size_t)M * D;

    PrepArgs pa;
    pa.csrc[0] = key_in;     pa.cdst[0] = xk;   pa.cn[0] = M * D;
    pa.csrc[1] = value_in;   pa.cdst[1] = xv;   pa.cn[1] = M * D;
    pa.csrc[2] = query_in;   pa.cdst[2] = xq;   pa.cn[2] = M * D;
    pa.csrc[3] = struct_emb; pa.cdst[3] = semb; pa.cn[3] = in_sizes[13];
    pa.csrc[4] = value_emb;  pa.cdst[4] = vemb; pa.cn[4] = in_sizes[14];
    pa.W[0] = Wq; pa.W[1] = Wk; pa.W[2] = Wv; pa.W[3] = Wo;
    pa.T[0] = WqT; pa.T[1] = WkT; pa.T[2] = WvT; pa.T[3] = WoT;
    prep_kernel<<<dim3((M * D) / 2048, 9), 256, 0, stream>>>(pa);

    GemmBatch qkv;
    qkv.A[0] = xq; qkv.Bt[0] = WqT; qkv.bias[0] = bq; qkv.out[0] = Qb; qkv.scale[0] = 0.125f; qkv.mode[0] = 1;
    qkv.A[1] = xk; qkv.Bt[1] = WkT; qkv.bias[1] = bk; qkv.out[1] = Kb; qkv.scale[1] = 1.0f;   qkv.mode[1] = 1;
    qkv.A[2] = xv; qkv.Bt[2] = WvT; qkv.bias[2] = bv; qkv.out[2] = Vt; qkv.scale[2] = 1.0f;   qkv.mode[2] = 2;
    gemm_mfma_kernel<<<dim3(D / BN, M / BM, 3), 256, 0, stream>>>(qkv, M, D, D);

    ast_kernel<<<dim3(L, B), 256, 0, stream>>>(Qb, mat, semb, vemb, Sast);

    attn_fused_kernel<<<dim3(L / 64, H, B), 256, 0, stream>>>(
        Qb, Kb, Vt, Sast, mask, attn_p, ctx);

    GemmBatch fin;
    fin.A[0] = ctx; fin.Bt[0] = WoT; fin.bias[0] = bo; fin.out[0] = out_p; fin.scale[0] = 1.0f; fin.mode[0] = 0;
    fin.A[1] = ctx; fin.Bt[1] = WoT; fin.bias[1] = bo; fin.out[1] = out_p; fin.scale[1] = 1.0f; fin.mode[1] = 0;
    fin.A[2] = ctx; fin.Bt[2] = WoT; fin.bias[2] = bo; fin.out[2] = out_p; fin.scale[2] = 1.0f; fin.mode[2] = 0;
    gemm_mfma_kernel<<<dim3(D / BN, M / BM, 1), 256, 0, stream>>>(fin, M, D, D);
}